// Round 4
// baseline (685.907 us; speedup 1.0000x reference)
//
#include <hip/hip_runtime.h>
#include <hip/hip_bf16.h>

// Problem constants (reference: B=1024, F=128, E=256, HEAD_NUM=8, d=32)
// Reference dtypes: ALL fp32 (inputs and output). bf16 is used only
// internally for MFMA operands; accumulation is fp32.
#define B_SZ 1024
#define F_SZ 128
#define E_SZ 256
#define H_NUM 8
#define D_SZ 32

typedef __bf16 bf16x8 __attribute__((ext_vector_type(8)));
typedef float f32x4 __attribute__((ext_vector_type(4)));

// LDS row strides (elements) — <=2-way bank aliasing on wave-wide reads.
#define STRQ 40    // Q/K head tiles (32 + 8)
#define STRP 136   // P and V^T tiles (128 + 8)

__device__ __forceinline__ bf16x8 frag_at(const __hip_bfloat16* p) {
  return *reinterpret_cast<const bf16x8*>(p);
}

// load 8 consecutive fp32 and round to a bf16x8 MFMA fragment
__device__ __forceinline__ bf16x8 cvt_frag(const float* p) {
  float4 a = *reinterpret_cast<const float4*>(p);
  float4 b = *reinterpret_cast<const float4*>(p + 4);
  bf16x8 r;
  r[0] = (__bf16)a.x; r[1] = (__bf16)a.y; r[2] = (__bf16)a.z; r[3] = (__bf16)a.w;
  r[4] = (__bf16)b.x; r[5] = (__bf16)b.y; r[6] = (__bf16)b.z; r[7] = (__bf16)b.w;
  return r;
}

// ---------------------------------------------------------------------------
// Kernel 1: transpose the four fp32 E x E weights into d_ws as bf16 WT[n][e]
// so MFMA B-fragments (8 k-contiguous elements per output column n) are
// direct 16B loads. 4 * 128 KB bf16 = 512 KB -> L2-resident afterwards.
// ---------------------------------------------------------------------------
__global__ void transpose_weights(const float* __restrict__ W0,
                                  const float* __restrict__ W1,
                                  const float* __restrict__ W2,
                                  const float* __restrict__ W3,
                                  __hip_bfloat16* __restrict__ WT) {
  __shared__ float tile[64][65];
  const int wsel = blockIdx.x >> 4;
  const float* W = wsel == 0 ? W0 : wsel == 1 ? W1 : wsel == 2 ? W2 : W3;
  __hip_bfloat16* T = WT + wsel * (E_SZ * E_SZ);
  const int t = blockIdx.x & 15;
  const int tr = (t >> 2) * 64, tc = (t & 3) * 64;
  for (int k = 0; k < 16; ++k) {
    int fl = k * 256 + threadIdx.x;
    int lr = fl >> 6, lc = fl & 63;
    tile[lr][lc] = W[(tr + lr) * E_SZ + tc + lc];
  }
  __syncthreads();
  for (int k = 0; k < 16; ++k) {
    int fl = k * 256 + threadIdx.x;
    int lr = fl >> 6, lc = fl & 63;
    T[(tc + lr) * E_SZ + tr + lc] = __float2bfloat16(tile[lc][lr]);
  }
}

// ---------------------------------------------------------------------------
// Kernel 2: fully fused per-batch attention. One block per batch element b,
// 512 threads = 8 waves; wave w owns rows 16w..16w+15 for every GEMM phase.
// X A-fragments are head-invariant -> hoisted once into 32 VGPRs/lane
// (fp32 global loads, bf16 convert). Static LDS = 64,000 B.
//
// MFMA 16x16x32 bf16 layouts (measured, learn_hip m89/m91):
//   A-frag: lane holds A[m = lane&15][k = (lane>>4)*8 + j], j=0..7
//   B-frag: lane holds B[k = (lane>>4)*8 + j][n = lane&15]
//   C/D:    lane reg r holds C[row = (lane>>4)*4 + r][col = lane&15]
// ---------------------------------------------------------------------------
__global__ __launch_bounds__(512)
void fused_attn(const float* __restrict__ Xg_all,
                const __hip_bfloat16* __restrict__ WT,  // 4 * [256][256] bf16^T
                float* __restrict__ out) {
  __shared__ __align__(16) __hip_bfloat16 Qs[F_SZ * STRQ];   // 10240 B
  __shared__ __align__(16) __hip_bfloat16 Ks[F_SZ * STRQ];   // 10240 B
  __shared__ __align__(16) __hip_bfloat16 VTs[D_SZ * STRP];  //  8704 B (V^T)
  __shared__ __align__(16) __hip_bfloat16 Ps[F_SZ * STRP];   // 34816 B

  const int tid  = threadIdx.x;
  const int wave = tid >> 6;
  const int lane = tid & 63;
  const int quad = lane >> 4;
  const int l16  = lane & 15;
  const int b    = blockIdx.x;
  const float* Xg = Xg_all + (size_t)b * (F_SZ * E_SZ);

  const int fbase = wave * 16;               // this wave's 16-row m-tile

  // hoist X A-fragments (head-invariant): X[fbase+l16][ks*32+quad*8 .. +8]
  bf16x8 xa[8];
  #pragma unroll
  for (int ks = 0; ks < 8; ++ks)
    xa[ks] = cvt_frag(Xg + (fbase + l16) * E_SZ + ks * 32 + quad * 8);

  for (int h = 0; h < H_NUM; ++h) {
    // ================= Phase 1: QKVR projection ==========================
    // C[f][n] = sum_e X[f][e] * Wsel[e][h*32 + n], n in 0..127 over
    // [Qh(0:32) | Kh | Vh | Rh].  B-frags read from WT (k-contiguous, L2).
    f32x4 acc[8];
    #pragma unroll
    for (int nt = 0; nt < 8; ++nt) acc[nt] = f32x4{0.f, 0.f, 0.f, 0.f};

    #pragma unroll
    for (int ks = 0; ks < 8; ++ks) {
      #pragma unroll
      for (int nt = 0; nt < 8; ++nt) {
        const __hip_bfloat16* wp = WT + (nt >> 1) * (E_SZ * E_SZ)
                                  + (h * 32 + (nt & 1) * 16 + l16) * E_SZ
                                  + ks * 32 + quad * 8;
        bf16x8 bw = frag_at(wp);
        acc[nt] = __builtin_amdgcn_mfma_f32_16x16x32_bf16(xa[ks], bw, acc[nt], 0, 0, 0);
      }
    }

    // Q,K row-major [f][d]; V transposed [d][f] (PV B-operand layout).
    // R (acc[6],acc[7]) stays in registers until the epilogue.
    #pragma unroll
    for (int reg = 0; reg < 4; ++reg) {
      int f = fbase + quad * 4 + reg;
      Qs[f * STRQ + l16]         = __float2bfloat16(acc[0][reg]);
      Qs[f * STRQ + 16 + l16]    = __float2bfloat16(acc[1][reg]);
      Ks[f * STRQ + l16]         = __float2bfloat16(acc[2][reg]);
      Ks[f * STRQ + 16 + l16]    = __float2bfloat16(acc[3][reg]);
      VTs[l16 * STRP + f]        = __float2bfloat16(acc[4][reg]);
      VTs[(16 + l16) * STRP + f] = __float2bfloat16(acc[5][reg]);
    }
    float r0[4], r1[4];
    #pragma unroll
    for (int reg = 0; reg < 4; ++reg) { r0[reg] = acc[6][reg]; r1[reg] = acc[7][reg]; }
    __syncthreads();

    // ================= Phase 2: S = Qh @ Kh^T (K=32 -> 1 MFMA/tile) ======
    f32x4 s[8];
    {
      bf16x8 aq = frag_at(Qs + (fbase + l16) * STRQ + quad * 8);
      #pragma unroll
      for (int nt = 0; nt < 8; ++nt) {
        bf16x8 bk = frag_at(Ks + (nt * 16 + l16) * STRQ + quad * 8);
        s[nt] = __builtin_amdgcn_mfma_f32_16x16x32_bf16(
            aq, bk, f32x4{0.f, 0.f, 0.f, 0.f}, 0, 0, 0);
      }
    }

    // ============ Phase 3: row softmax (in regs) + P -> LDS ==============
    // Row r = fbase + quad*4 + reg lives on the 16 lanes sharing `quad`;
    // cols = nt*16 + l16. Shuffle-reduce within the 16-lane group.
    #pragma unroll
    for (int reg = 0; reg < 4; ++reg) {
      float m = s[0][reg];
      #pragma unroll
      for (int nt = 1; nt < 8; ++nt) m = fmaxf(m, s[nt][reg]);
      #pragma unroll
      for (int off = 8; off >= 1; off >>= 1) m = fmaxf(m, __shfl_xor(m, off));
      float sum = 0.f;
      #pragma unroll
      for (int nt = 0; nt < 8; ++nt) {
        float e = __expf(s[nt][reg] - m);
        s[nt][reg] = e;
        sum += e;
      }
      #pragma unroll
      for (int off = 8; off >= 1; off >>= 1) sum += __shfl_xor(sum, off);
      float inv = 1.f / sum;
      int f = fbase + quad * 4 + reg;
      #pragma unroll
      for (int nt = 0; nt < 8; ++nt)
        Ps[f * STRP + nt * 16 + l16] = __float2bfloat16(s[nt][reg] * inv);
    }
    __syncthreads();

    // ================= Phase 4: O = P @ V (K=128 -> 4 k-steps) ===========
    f32x4 o0 = {0.f, 0.f, 0.f, 0.f}, o1 = {0.f, 0.f, 0.f, 0.f};
    #pragma unroll
    for (int ks = 0; ks < 4; ++ks) {
      bf16x8 ap  = frag_at(Ps + (fbase + l16) * STRP + ks * 32 + quad * 8);
      bf16x8 bv0 = frag_at(VTs + l16 * STRP        + ks * 32 + quad * 8);
      bf16x8 bv1 = frag_at(VTs + (16 + l16) * STRP + ks * 32 + quad * 8);
      o0 = __builtin_amdgcn_mfma_f32_16x16x32_bf16(ap, bv0, o0, 0, 0, 0);
      o1 = __builtin_amdgcn_mfma_f32_16x16x32_bf16(ap, bv1, o1, 0, 0, 0);
    }

    // ===== Epilogue: + residual, relu (NaN-PROPAGATING), fp32 store ======
    // relu as (v<0)?0:v so a numerics bug shows as a huge error, not zeros.
    #pragma unroll
    for (int reg = 0; reg < 4; ++reg) {
      int f = fbase + quad * 4 + reg;
      float v0 = o0[reg] + r0[reg]; v0 = (v0 < 0.f) ? 0.f : v0;
      float v1 = o1[reg] + r1[reg]; v1 = (v1 < 0.f) ? 0.f : v1;
      size_t base = ((size_t)b * F_SZ + f) * E_SZ + h * D_SZ;
      out[base + l16]      = v0;
      out[base + 16 + l16] = v1;
    }
    __syncthreads();   // protect Qs/Ks/VTs/Ps reuse by next head
  }
}

// ---------------------------------------------------------------------------
extern "C" void kernel_launch(void* const* d_in, const int* in_sizes, int n_in,
                              void* d_out, int out_size, void* d_ws, size_t ws_size,
                              hipStream_t stream) {
  const float* X  = (const float*)d_in[0];
  const float* Wq = (const float*)d_in[1];
  const float* Wk = (const float*)d_in[2];
  const float* Wv = (const float*)d_in[3];
  const float* Wr = (const float*)d_in[4];
  float* out = (float*)d_out;
  __hip_bfloat16* WT = (__hip_bfloat16*)d_ws;  // 4*256*256*2 = 512 KB

  (void)hipGetLastError();  // clear stale error state
  transpose_weights<<<64, 256, 0, stream>>>(Wq, Wk, Wv, Wr, WT);
  fused_attn<<<B_SZ, 512, 0, stream>>>(X, WT, out);

  // Launch-failure exfiltration: poison start of d_out with 0x7F bytes
  // (fp32 ~3.4e38) so a rejected launch prints an unmistakable absmax
  // instead of silently comparing zeros. No-op when launches succeed.
  hipError_t err = hipGetLastError();
  if (err != hipSuccess) {
    hipMemsetAsync(d_out, 0x7F, 1024, stream);
  }
}